// Round 14
// baseline (238.444 us; speedup 1.0000x reference)
//
#include <hip/hip_runtime.h>

#define D_MODEL 2048
#define GHD 512        // NUM_KV_GROUPS * HEAD_DIM
#define HD 128
#define NQH 16
#define B_SZ 2
#define SEQ 2048
#define M_TOT (B_SZ * SEQ)   // 4096

typedef _Float16 f16;
typedef __fp16 h16x2 __attribute__((ext_vector_type(2)));   // cvt_pkrtz native type
typedef _Float16 f16x4 __attribute__((ext_vector_type(4)));
typedef _Float16 f16x8 __attribute__((ext_vector_type(8)));
typedef float f32x4 __attribute__((ext_vector_type(4)));

typedef const __attribute__((address_space(1))) void gvoid;
typedef __attribute__((address_space(3))) void lvoid;
typedef __attribute__((address_space(3))) f16 lf16;

// raw barrier (no vmcnt(0) drain) with compiler fences
#define BAR() do { asm volatile("" ::: "memory"); \
                   __builtin_amdgcn_s_barrier();  \
                   asm volatile("" ::: "memory"); } while (0)
#define WAIT_VM8() asm volatile("s_waitcnt vmcnt(8)" ::: "memory")
#define WAIT_VM0() asm volatile("s_waitcnt vmcnt(0)" ::: "memory")
#define WAIT_LGKM(N) do { asm volatile("s_waitcnt lgkmcnt(" #N ")" ::: "memory"); \
                          __builtin_amdgcn_sched_barrier(0); } while (0)

// hardware transpose read: with per-lane addr = base + l*8B, lane l elem j
// reads f16 at base_f16[OFF/2 + (l>>4)*64 + j*16 + (l&15)]
template<int OFF>
__device__ __forceinline__ f16x4 tr16(unsigned a) {
    f16x4 d;
    asm volatile("ds_read_b64_tr_b16 %0, %1 offset:%2"
                 : "=v"(d) : "v"(a), "i"(OFF));
    return d;
}

// ---------------------------------------------------------------------------
// x (fp32) -> f16 cast, elementwise
// ---------------------------------------------------------------------------
__global__ __launch_bounds__(256) void cast_f16(
    const float* __restrict__ X, f16* __restrict__ Xh)
{
    const size_t i = ((size_t)blockIdx.x * 256 + threadIdx.x) * 8;
    const float4 v0 = *(const float4*)(X + i);
    const float4 v1 = *(const float4*)(X + i + 4);
    f16x8 h;
    h[0] = (f16)v0.x; h[1] = (f16)v0.y; h[2] = (f16)v0.z; h[3] = (f16)v0.w;
    h[4] = (f16)v1.x; h[5] = (f16)v1.y; h[6] = (f16)v1.z; h[7] = (f16)v1.w;
    *(f16x8*)(Xh + i) = h;
}

// ---------------------------------------------------------------------------
// Transpose + f16 cast: W[K][N] fp32 -> Th[(row_off+n)][K] f16
// ---------------------------------------------------------------------------
__global__ __launch_bounds__(256) void transpose_cast(
    const float* __restrict__ W, f16* __restrict__ Th,
    int K, int N, int row_off)
{
    __shared__ float Ls[32][33];
    const int t = threadIdx.x;
    const int n0 = blockIdx.x << 5, k0 = blockIdx.y << 5;
    {
        const int kr = t >> 3, nq = (t & 7) << 2;
        const float4 v = *(const float4*)&W[(size_t)(k0 + kr) * N + n0 + nq];
        Ls[kr][nq + 0] = v.x; Ls[kr][nq + 1] = v.y;
        Ls[kr][nq + 2] = v.z; Ls[kr][nq + 3] = v.w;
    }
    __syncthreads();
    const int nr = t >> 3, kq = (t & 7) << 2;
    f16x4 hv;
#pragma unroll
    for (int e = 0; e < 4; ++e) hv[e] = (f16)Ls[kq + e][nr];
    *(f16x4*)&Th[(size_t)(row_off + n0 + nr) * K + k0 + kq] = hv;
}

// ---------------------------------------------------------------------------
// 1-term f16 MFMA GEMM, templated BK (barrier phases = K/BK).
// QKV mode: N=3072 fused projection — 3-way epilogue routing (Q|K|V) at the
// 16-aligned boundaries 2048/2560; f16 outs; qscale folded into Q columns.
// else: 1-way fp32 out + bias (O-projection).
// BM=128, 256 threads (4 waves). LDK=BK+8 pad (bank-uniform LDS ops).
// XCD-aware block swizzle (T1). Last-iter prefetch over-reads stay in d_ws.
// ---------------------------------------------------------------------------
template<int BN, int BK, bool QKV>
__global__ __launch_bounds__(256) void gemm_f16(
    const f16* __restrict__ Agh, const f16* __restrict__ BTh,
    const float* __restrict__ b0, const float* __restrict__ b1,
    const float* __restrict__ b2,
    f16* __restrict__ Qo, f16* __restrict__ Ko, f16* __restrict__ Vo,
    float* __restrict__ Fo,
    int K, float qscale)
{
    constexpr int WN = BN / 64;           // waves along n
    constexpr int WM = 4 / WN;            // waves along m
    constexpr int WI = 128 / (WM * 16);   // m-frags per wave
    constexpr int LDK = BK + 8;           // padded row (f16)
    constexpr int CH  = BK / 8;           // 16B chunks per row
    constexpr int RPP = 256 / CH;         // rows staged per pass
    constexpr int AP  = 128 / RPP;        // A staging passes
    constexpr int BP  = BN / RPP;         // B staging passes
    constexpr int NC  = BK / 32;          // MFMA k-steps per tile

    __shared__ f16 Ah[128 * LDK];
    __shared__ f16 Bh[BN * LDK];

    const int tid = threadIdx.x;
    const int l = tid & 63, w = tid >> 6;
    const int l15 = l & 15, lq = l >> 4;
    const int wr = w / WN, wc = w % WN;

    // XCD swizzle: contiguous chunk of tiles per XCD (nwg divisible by 8)
    const int nwgx = gridDim.x;
    const int orig = blockIdx.y * nwgx + blockIdx.x;
    const int cpx = (nwgx * gridDim.y) >> 3;
    const int sw = (orig & 7) * cpx + (orig >> 3);
    const int m0 = (sw / nwgx) << 7;
    const int n0 = (sw % nwgx) * BN;

    f32x4 acc[WI][4];
#pragma unroll
    for (int i = 0; i < WI; ++i)
#pragma unroll
        for (int j = 0; j < 4; ++j) acc[i][j] = (f32x4){0.f, 0.f, 0.f, 0.f};

    const int srow = tid / CH;
    const int skc  = (tid % CH) * 8;
    const f16* Ap = Agh + (size_t)(m0 + srow) * K + skc;
    const f16* Bp = BTh + (size_t)(n0 + srow) * K + skc;

    f16x8 av[AP], bvv[BP];
#pragma unroll
    for (int p = 0; p < AP; ++p)
        av[p] = *(const f16x8*)(Ap + (size_t)(p * RPP) * K);
#pragma unroll
    for (int p = 0; p < BP; ++p)
        bvv[p] = *(const f16x8*)(Bp + (size_t)(p * RPP) * K);

    for (int k0 = 0; k0 < K; k0 += BK) {
        __syncthreads();   // previous iteration's fragment reads done
#pragma unroll
        for (int p = 0; p < AP; ++p)
            *(f16x8*)&Ah[(srow + p * RPP) * LDK + skc] = av[p];
#pragma unroll
        for (int p = 0; p < BP; ++p)
            *(f16x8*)&Bh[(srow + p * RPP) * LDK + skc] = bvv[p];
        __syncthreads();

        // prefetch next k0 (flies under MFMA; last-iter over-read stays in ws)
        const int kn = k0 + BK;
#pragma unroll
        for (int p = 0; p < AP; ++p)
            av[p] = *(const f16x8*)(Ap + (size_t)(p * RPP) * K + kn);
#pragma unroll
        for (int p = 0; p < BP; ++p)
            bvv[p] = *(const f16x8*)(Bp + (size_t)(p * RPP) * K + kn);

#pragma unroll
        for (int c = 0; c < NC; ++c) {
            f16x8 afh[WI];
#pragma unroll
            for (int i = 0; i < WI; ++i) {
                const int row = wr * (WI * 16) + i * 16 + l15;
                afh[i] = *(const f16x8*)&Ah[row * LDK + c * 32 + lq * 8];
            }
#pragma unroll
            for (int j = 0; j < 4; ++j) {
                const int bn = wc * 64 + j * 16 + l15;
                const f16x8 bfh = *(const f16x8*)&Bh[bn * LDK + c * 32 + lq * 8];
#pragma unroll
                for (int i = 0; i < WI; ++i)
                    acc[i][j] = __builtin_amdgcn_mfma_f32_16x16x32_f16(afh[i], bfh, acc[i][j], 0, 0, 0);
            }
        }
    }

#pragma unroll
    for (int j = 0; j < 4; ++j) {
        const int ng = n0 + wc * 64 + j * 16 + l15;
        float bias, osc = 1.f;
        f16* outp = nullptr;
        int nc = ng, ldc = 2048;
        if constexpr (QKV) {
            if (ng < 2048)      { bias = b0[ng];        outp = Qo; osc = qscale; }
            else if (ng < 2560) { bias = b1[ng - 2048]; outp = Ko; nc = ng - 2048; ldc = 512; }
            else                { bias = b2[ng - 2560]; outp = Vo; nc = ng - 2560; ldc = 512; }
        } else {
            bias = b0[ng];
        }
#pragma unroll
        for (int i = 0; i < WI; ++i) {
            const int mg = m0 + wr * (WI * 16) + i * 16 + lq * 4;
#pragma unroll
            for (int r = 0; r < 4; ++r) {
                const float v = (acc[i][j][r] + bias) * osc;
                if constexpr (QKV)
                    outp[(size_t)(mg + r) * ldc + nc] = (f16)v;
                else
                    Fo[(size_t)(mg + r) * 2048 + nc] = v;
            }
        }
    }
}

#define SHUF8(x, y) __builtin_shufflevector(x, y, 0, 1, 2, 3, 4, 5, 6, 7)

// ---------------------------------------------------------------------------
// fp16-MFMA flash attention v6.1 (unchanged from round 13 — passed):
// 4 waves x 32 q-rows, swapped QK^T (in-register P via cvt_pkrtz, zero P LDS),
// permuted V tr16 subtiles, per-q ballot-deferred softmax, double-buffered
// K/V via global_load_lds + counted vmcnt + raw barriers, f16 AO out.
// ---------------------------------------------------------------------------
__global__ __launch_bounds__(256, 2) void flash_attn_mfma(
    const f16* __restrict__ Q, const f16* __restrict__ Kp,
    const f16* __restrict__ Vp, f16* __restrict__ AOh)
{
    __shared__ f16 KsA[2][64 * 128];   // 32 KB
    __shared__ f16 VtA[2][64 * 128];   // 32 KB (tr16 subtiled, permuted rows)

    const int tid = threadIdx.x;
    const int w = tid >> 6, l = tid & 63;
    const int l15 = l & 15, lq = l >> 4;
    const int b = blockIdx.z, h = blockIdx.y, g = h >> 2;
    const int q0 = blockIdx.x << 7;    // 128 q-rows per block

    const f16* Qb = Q + (size_t)(b * SEQ + q0) * D_MODEL + h * HD;
    const f16* Kb = Kp + (size_t)b * SEQ * GHD + g * HD;
    const f16* Vb = Vp + (size_t)b * SEQ * GHD + g * HD;

    f16x8 aq[2][4];
#pragma unroll
    for (int rg = 0; rg < 2; ++rg) {
        const f16* qrow = Qb + (size_t)(w * 32 + rg * 16 + l15) * D_MODEL;
#pragma unroll
        for (int c = 0; c < 4; ++c)
            aq[rg][c] = *(const f16x8*)(qrow + c * 32 + lq * 8);
    }

    lf16* Ks3 = (lf16*)&KsA[0][0];
    lf16* Vt3 = (lf16*)&VtA[0][0];
    const f16* ksrc[4]; lf16* kdst[4];
    const f16* vsrc[4]; lf16* vdst[4];
#pragma unroll
    for (int i = 0; i < 4; ++i) {
        const int s = tid + (i << 8);
        {
            const int row = s >> 4, ul = s & 15;
            ksrc[i] = Kb + (size_t)row * GHD + ((ul ^ (row & 7)) << 3);
            kdst[i] = Ks3 + s * 8;
        }
        {
            const int dbit = s & 1, kvlo = (s >> 1) & 3, vlq = (s >> 3) & 3;
            const int jh = (s >> 5) & 1, kc = (s >> 6) & 1, dsub = s >> 7;
            const int kv = (kc << 5) | (jh << 4) | (vlq << 2) | kvlo;
            vsrc[i] = Vb + (size_t)kv * GHD + ((dsub << 4) | (dbit << 3));
            vdst[i] = Vt3 + s * 8;
        }
    }
    const unsigned vta0 = (unsigned)(size_t)(Vt3 + l * 4);
    const unsigned vta1 = vta0 + 16384;

    f32x4 acc_o[2][8];
#pragma unroll
    for (int rg = 0; rg < 2; ++rg)
#pragma unroll
        for (int i = 0; i < 8; ++i) acc_o[rg][i] = (f32x4){0.f, 0.f, 0.f, 0.f};
    float m_q[2] = {-1e30f, -1e30f};
    float l_q[2] = {0.f, 0.f};

    auto issue_tile = [&](int buf, int tile) {
        const size_t koff = (size_t)tile * 64 * GHD;
        const int KO = buf << 13;
#pragma unroll
        for (int i = 0; i < 4; ++i)
            __builtin_amdgcn_global_load_lds((gvoid*)(ksrc[i] + koff),
                                             (lvoid*)(kdst[i] + KO), 16, 0, 0);
#pragma unroll
        for (int i = 0; i < 4; ++i)
            __builtin_amdgcn_global_load_lds((gvoid*)(vsrc[i] + koff),
                                             (lvoid*)(vdst[i] + KO), 16, 0, 0);
    };

    auto compute_tile = [&](const f16* KsB, unsigned vtaB) {
        f32x4 sa[2][4];
        __builtin_amdgcn_s_setprio(1);
#pragma unroll
        for (int cb = 0; cb < 4; ++cb) {
            sa[0][cb] = (f32x4){0.f, 0.f, 0.f, 0.f};
            sa[1][cb] = (f32x4){0.f, 0.f, 0.f, 0.f};
#pragma unroll
            for (int c = 0; c < 4; ++c) {
                const int rk = cb * 16 + l15;
                const f16x8 bk = *(const f16x8*)&KsB[rk * 128 + (((c * 4 + lq) ^ (rk & 7)) << 3)];
                sa[0][cb] = __builtin_amdgcn_mfma_f32_16x16x32_f16(bk, aq[0][c], sa[0][cb], 0, 0, 0);
                sa[1][cb] = __builtin_amdgcn_mfma_f32_16x16x32_f16(bk, aq[1][c], sa[1][cb], 0, 0, 0);
            }
        }
        __builtin_amdgcn_s_setprio(0);

#pragma unroll
        for (int rg = 0; rg < 2; ++rg) {
            float gm = sa[rg][0][0];
#pragma unroll
            for (int cb = 0; cb < 4; ++cb)
#pragma unroll
                for (int reg = 0; reg < 4; ++reg)
                    gm = fmaxf(gm, sa[rg][cb][reg]);
            gm = fmaxf(gm, __shfl_xor(gm, 16));
            gm = fmaxf(gm, __shfl_xor(gm, 32));
            if (__ballot(gm > m_q[rg] + 11.5f)) {
                const float mnew = fmaxf(m_q[rg], gm);
                const float alpha = __builtin_amdgcn_exp2f(m_q[rg] - mnew);
                m_q[rg] = mnew;
                l_q[rg] *= alpha;
                f32x4 av;
#pragma unroll
                for (int reg = 0; reg < 4; ++reg)
                    av[reg] = __shfl(alpha, lq * 4 + reg);
#pragma unroll
                for (int db = 0; db < 8; ++db) acc_o[rg][db] *= av;
            }
        }

        f16x4 va0 = tr16<0>(vtaB),    vb0 = tr16<512>(vtaB);
        f16x4 va1 = tr16<1024>(vtaB), vb1 = tr16<1536>(vtaB);
        f16x4 ca0 = tr16<2048>(vtaB), cb0 = tr16<2560>(vtaB);
        f16x4 ca1 = tr16<3072>(vtaB), cb1 = tr16<3584>(vtaB);

        f16x8 pa[2][2];
#pragma unroll
        for (int rg = 0; rg < 2; ++rg) {
            float ps = 0.f;
#pragma unroll
            for (int cb = 0; cb < 4; ++cb)
#pragma unroll
                for (int reg = 0; reg < 4; ++reg) {
                    const float p = __builtin_amdgcn_exp2f(sa[rg][cb][reg] - m_q[rg]);
                    sa[rg][cb][reg] = p;
                    ps += p;
                }
            l_q[rg] += ps;
#pragma unroll
            for (int kc = 0; kc < 2; ++kc) {
                union { h16x2 h2[4]; f16x8 h8; } u;
                u.h2[0] = __builtin_amdgcn_cvt_pkrtz(sa[rg][2 * kc][0], sa[rg][2 * kc][1]);
                u.h2[1] = __builtin_amdgcn_cvt_pkrtz(sa[rg][2 * kc][2], sa[rg][2 * kc][3]);
                u.h2[2] = __builtin_amdgcn_cvt_pkrtz(sa[rg][2 * kc + 1][0], sa[rg][2 * kc + 1][1]);
                u.h2[3] = __builtin_amdgcn_cvt_pkrtz(sa[rg][2 * kc + 1][2], sa[rg][2 * kc + 1][3]);
                pa[rg][kc] = u.h8;
            }
        }

        WAIT_LGKM(4);
        f16x8 v0 = SHUF8(va0, vb0), v1 = SHUF8(va1, vb1);
#pragma unroll
        for (int db = 0; db < 8; ++db) {
            f16x4 ma0, mb0, ma1, mb1;
            if (db < 6) {
                switch (db) {
                case 0: ma0=tr16<4096>(vtaB);  mb0=tr16<4608>(vtaB);  ma1=tr16<5120>(vtaB);  mb1=tr16<5632>(vtaB);  break;
                case 1: ma0=tr16<6144>(vtaB);  mb0=tr16<6656>(vtaB);  ma1=tr16<7168>(vtaB);  mb1=tr16<7680>(vtaB);  break;
                case 2: ma0=tr16<8192>(vtaB);  mb0=tr16<8704>(vtaB);  ma1=tr16<9216>(vtaB);  mb1=tr16<9728>(vtaB);  break;
                case 3: ma0=tr16<10240>(vtaB); mb0=tr16<10752>(vtaB); ma1=tr16<11264>(vtaB); mb1=tr16<11776>(vtaB); break;
                case 4: ma0=tr16<12288>(vtaB); mb0=tr16<12800>(vtaB); ma1=tr16<13312>(vtaB); mb1=tr16<13824>(vtaB); break;
                default:ma0=tr16<14336>(vtaB); mb0=tr16<14848>(vtaB); ma1=tr16<15360>(vtaB); mb1=tr16<15872>(vtaB); break;
                }
                WAIT_LGKM(4);
            } else if (db == 6) {
                WAIT_LGKM(0);
            }
            f16x8 n0, n1;
            if (db < 7) { n0 = SHUF8(ca0, cb0); n1 = SHUF8(ca1, cb1); }
            __builtin_amdgcn_s_setprio(1);
            acc_o[0][db] = __builtin_amdgcn_mfma_f32_16x16x32_f16(pa[0][0], v0, acc_o[0][db], 0, 0, 0);
            acc_o[1][db] = __builtin_amdgcn_mfma_f32_16x16x32_f16(pa[1][0], v0, acc_o[1][db], 0, 0, 0);
            acc_o[0][db] = __builtin_amdgcn_mfma_f32_16x16x32_f16(pa[0][1], v1, acc_o[0][db], 0, 0, 0);
            acc_o[1][db] = __builtin_amdgcn_mfma_f32_16x16x32_f16(pa[1][1], v1, acc_o[1][db], 0, 0, 0);
            __builtin_amdgcn_s_setprio(0);
            if (db < 7) {
                v0 = n0; v1 = n1;
                ca0 = ma0; cb0 = mb0; ca1 = ma1; cb1 = mb1;
            }
        }
    };

    issue_tile(0, 0);
#pragma unroll 1
    for (int t2 = 0; t2 < 16; ++t2) {
        const int kt0 = t2 << 1;
        issue_tile(1, kt0 + 1);
        WAIT_VM8();
        BAR();
        compute_tile(&KsA[0][0], vta0);
        BAR();
        if (t2 < 15) {
            issue_tile(0, kt0 + 2);
            WAIT_VM8();
        } else {
            WAIT_VM0();
        }
        BAR();
        compute_tile(&KsA[1][0], vta1);
        BAR();
    }

    const size_t obase = (size_t)(b * SEQ + q0 + w * 32) * D_MODEL + h * HD;
#pragma unroll
    for (int rg = 0; rg < 2; ++rg) {
        float lr = l_q[rg];
        lr += __shfl_xor(lr, 16);
        lr += __shfl_xor(lr, 32);
        float inv_l[4];
#pragma unroll
        for (int reg = 0; reg < 4; ++reg)
            inv_l[reg] = 1.f / __shfl(lr, lq * 4 + reg);
#pragma unroll
        for (int db = 0; db < 8; ++db) {
#pragma unroll
            for (int reg = 0; reg < 4; ++reg) {
                const size_t off = obase + (size_t)(rg * 16 + lq * 4 + reg) * D_MODEL + db * 16 + l15;
                AOh[off] = (f16)(acc_o[rg][db][reg] * inv_l[reg]);
            }
        }
    }
}

extern "C" void kernel_launch(void* const* d_in, const int* in_sizes, int n_in,
                              void* d_out, int out_size, void* d_ws, size_t ws_size,
                              hipStream_t stream)
{
    const float* x  = (const float*)d_in[0];
    const float* Wq = (const float*)d_in[1];
    const float* bq = (const float*)d_in[2];
    const float* Wk = (const float*)d_in[3];
    const float* bk = (const float*)d_in[4];
    const float* Wv = (const float*)d_in[5];
    const float* bv = (const float*)d_in[6];
    const float* Wo = (const float*)d_in[7];
    const float* bo = (const float*)d_in[8];
    float* out = (float*)d_out;

    // workspace (f16 units), total 27,262,976 f16 = 54.5 MB (<= 83.9 proven).
    // WqkvT = [Wq^T (2048 rows) | Wk^T (512) | Wv^T (512)] contiguous -> the
    // fused QKV GEMM's B. Wo^T later reuses rows 0..2047 of the same slot.
    // AOh aliases xh (x dead after fused QKV GEMM). Prefetch over-reads
    // (<=4 KB past any array) land in the next ws region — harmless.
    f16* base   = (f16*)d_ws;
    f16* xh     = base;                 // 8388608
    f16* WqkvT  = base + 8388608;       // 6291456 (3072 rows x 2048)
    f16* Qp     = base + 14680064;      // 8388608
    f16* Kp     = base + 23068672;      // 2097152
    f16* Vp     = base + 25165824;      // 2097152 -> end 27262976
    f16* AOh    = xh;

    const dim3 blk(256);
    // 1/sqrt(128) * log2(e): scores arrive in log2 units for exp2-direct softmax
    const float qscale = 0.08838834764831845f * 1.4426950408889634f;

    cast_f16<<<dim3(M_TOT * D_MODEL / 8 / 256), blk, 0, stream>>>(x, xh);
    transpose_cast<<<dim3(64, 64), blk, 0, stream>>>(Wq, WqkvT, 2048, 2048, 0);
    transpose_cast<<<dim3(16, 64), blk, 0, stream>>>(Wk, WqkvT, 2048, 512, 2048);
    transpose_cast<<<dim3(16, 64), blk, 0, stream>>>(Wv, WqkvT, 2048, 512, 2560);

    // fused Q|K|V projection: N=3072, 768 blocks (3/CU), BK=64
    gemm_f16<128, 64, true><<<dim3(24, 32), blk, 0, stream>>>(
        xh, WqkvT, bq, bk, bv, Qp, Kp, Vp, nullptr, 2048, qscale);

    // Wo^T into rows 0..2047 of the (now dead) WqkvT slot
    transpose_cast<<<dim3(64, 64), blk, 0, stream>>>(Wo, WqkvT, 2048, 2048, 0);

    flash_attn_mfma<<<dim3(SEQ / 128, NQH, B_SZ), blk, 0, stream>>>(Qp, Kp, Vp, AOh);

    // O projection: BK=128 (16 barrier phases), fp32 out
    gemm_f16<128, 128, false><<<dim3(16, 32), blk, 0, stream>>>(
        AOh, WqkvT, bo, bo, bo, nullptr, nullptr, nullptr, out, 2048, 1.0f);
}

// Round 15
// 227.935 us; speedup vs baseline: 1.0461x; 1.0461x over previous
//
#include <hip/hip_runtime.h>

#define D_MODEL 2048
#define GHD 512        // NUM_KV_GROUPS * HEAD_DIM
#define HD 128
#define NQH 16
#define B_SZ 2
#define SEQ 2048
#define M_TOT (B_SZ * SEQ)   // 4096

typedef _Float16 f16;
typedef __fp16 h16x2 __attribute__((ext_vector_type(2)));   // cvt_pkrtz native type
typedef _Float16 f16x4 __attribute__((ext_vector_type(4)));
typedef _Float16 f16x8 __attribute__((ext_vector_type(8)));
typedef float f32x4 __attribute__((ext_vector_type(4)));

typedef const __attribute__((address_space(1))) void gvoid;
typedef __attribute__((address_space(3))) void lvoid;
typedef __attribute__((address_space(3))) f16 lf16;

// raw barrier (no vmcnt(0) drain) with compiler fences
#define BAR() do { asm volatile("" ::: "memory"); \
                   __builtin_amdgcn_s_barrier();  \
                   asm volatile("" ::: "memory"); } while (0)
#define WAIT_VM8() asm volatile("s_waitcnt vmcnt(8)" ::: "memory")
#define WAIT_VM0() asm volatile("s_waitcnt vmcnt(0)" ::: "memory")
#define WAIT_LGKM(N) do { asm volatile("s_waitcnt lgkmcnt(" #N ")" ::: "memory"); \
                          __builtin_amdgcn_sched_barrier(0); } while (0)

// hardware transpose read: with per-lane addr = base + l*8B, lane l elem j
// reads f16 at base_f16[OFF/2 + (l>>4)*64 + j*16 + (l&15)]
template<int OFF>
__device__ __forceinline__ f16x4 tr16(unsigned a) {
    f16x4 d;
    asm volatile("ds_read_b64_tr_b16 %0, %1 offset:%2"
                 : "=v"(d) : "v"(a), "i"(OFF));
    return d;
}

// ---------------------------------------------------------------------------
// x (fp32) -> f16 cast, elementwise
// ---------------------------------------------------------------------------
__global__ __launch_bounds__(256) void cast_f16(
    const float* __restrict__ X, f16* __restrict__ Xh)
{
    const size_t i = ((size_t)blockIdx.x * 256 + threadIdx.x) * 8;
    const float4 v0 = *(const float4*)(X + i);
    const float4 v1 = *(const float4*)(X + i + 4);
    f16x8 h;
    h[0] = (f16)v0.x; h[1] = (f16)v0.y; h[2] = (f16)v0.z; h[3] = (f16)v0.w;
    h[4] = (f16)v1.x; h[5] = (f16)v1.y; h[6] = (f16)v1.z; h[7] = (f16)v1.w;
    *(f16x8*)(Xh + i) = h;
}

// ---------------------------------------------------------------------------
// Transpose + f16 cast: W[K][N] fp32 -> Th[(row_off+n)][K] f16
// ---------------------------------------------------------------------------
__global__ __launch_bounds__(256) void transpose_cast(
    const float* __restrict__ W, f16* __restrict__ Th,
    int K, int N, int row_off)
{
    __shared__ float Ls[32][33];
    const int t = threadIdx.x;
    const int n0 = blockIdx.x << 5, k0 = blockIdx.y << 5;
    {
        const int kr = t >> 3, nq = (t & 7) << 2;
        const float4 v = *(const float4*)&W[(size_t)(k0 + kr) * N + n0 + nq];
        Ls[kr][nq + 0] = v.x; Ls[kr][nq + 1] = v.y;
        Ls[kr][nq + 2] = v.z; Ls[kr][nq + 3] = v.w;
    }
    __syncthreads();
    const int nr = t >> 3, kq = (t & 7) << 2;
    f16x4 hv;
#pragma unroll
    for (int e = 0; e < 4; ++e) hv[e] = (f16)Ls[kq + e][nr];
    *(f16x4*)&Th[(size_t)(row_off + n0 + nr) * K + k0 + kq] = hv;
}

// ---------------------------------------------------------------------------
// 1-term f16 MFMA GEMM, templated BK (barrier phases = K/BK): round-13
// structure (reverted from the round-14 fusion, which blew past per-XCD L2).
// BM=128, 256 threads (4 waves). LDK=BK+8 pad (bank-uniform LDS ops).
// XCD-aware block swizzle (T1). Last-iter prefetch over-reads stay in d_ws.
// ---------------------------------------------------------------------------
template<int BN, int BK, bool OUT32>
__global__ __launch_bounds__(256) void gemm_bk(
    const f16* __restrict__ Agh,
    const f16* __restrict__ BTh,
    const float* __restrict__ bias0, const float* __restrict__ bias1,
    void* __restrict__ C0v, void* __restrict__ C1v,
    int Nsplit, int ld0, int ld1, int K, float outscale)
{
    constexpr int WN = BN / 64;           // waves along n
    constexpr int WM = 4 / WN;            // waves along m
    constexpr int WI = 128 / (WM * 16);   // m-frags per wave
    constexpr int LDK = BK + 8;           // padded row (f16)
    constexpr int CH  = BK / 8;           // 16B chunks per row
    constexpr int RPP = 256 / CH;         // rows staged per pass
    constexpr int AP  = 128 / RPP;        // A staging passes
    constexpr int BP  = BN / RPP;         // B staging passes
    constexpr int NC  = BK / 32;          // MFMA k-steps per tile

    __shared__ f16 Ah[128 * LDK];
    __shared__ f16 Bh[BN * LDK];

    const int tid = threadIdx.x;
    const int l = tid & 63, w = tid >> 6;
    const int l15 = l & 15, lq = l >> 4;
    const int wr = w / WN, wc = w % WN;

    // XCD swizzle: contiguous chunk of tiles per XCD (nwg = 512, div by 8)
    const int nwgx = gridDim.x;
    const int orig = blockIdx.y * nwgx + blockIdx.x;
    const int cpx = (nwgx * gridDim.y) >> 3;
    const int sw = (orig & 7) * cpx + (orig >> 3);
    const int m0 = (sw / nwgx) << 7;
    const int n0 = (sw % nwgx) * BN;

    f32x4 acc[WI][4];
#pragma unroll
    for (int i = 0; i < WI; ++i)
#pragma unroll
        for (int j = 0; j < 4; ++j) acc[i][j] = (f32x4){0.f, 0.f, 0.f, 0.f};

    const int srow = tid / CH;
    const int skc  = (tid % CH) * 8;
    const f16* Ap = Agh + (size_t)(m0 + srow) * K + skc;
    const f16* Bp = BTh + (size_t)(n0 + srow) * K + skc;

    f16x8 av[AP], bv[BP];
#pragma unroll
    for (int p = 0; p < AP; ++p)
        av[p] = *(const f16x8*)(Ap + (size_t)(p * RPP) * K);
#pragma unroll
    for (int p = 0; p < BP; ++p)
        bv[p] = *(const f16x8*)(Bp + (size_t)(p * RPP) * K);

    for (int k0 = 0; k0 < K; k0 += BK) {
        __syncthreads();   // previous iteration's fragment reads done
#pragma unroll
        for (int p = 0; p < AP; ++p)
            *(f16x8*)&Ah[(srow + p * RPP) * LDK + skc] = av[p];
#pragma unroll
        for (int p = 0; p < BP; ++p)
            *(f16x8*)&Bh[(srow + p * RPP) * LDK + skc] = bv[p];
        __syncthreads();

        // prefetch next k0 (flies under MFMA; last-iter over-read stays in ws)
        const int kn = k0 + BK;
#pragma unroll
        for (int p = 0; p < AP; ++p)
            av[p] = *(const f16x8*)(Ap + (size_t)(p * RPP) * K + kn);
#pragma unroll
        for (int p = 0; p < BP; ++p)
            bv[p] = *(const f16x8*)(Bp + (size_t)(p * RPP) * K + kn);

#pragma unroll
        for (int c = 0; c < NC; ++c) {
            f16x8 afh[WI];
#pragma unroll
            for (int i = 0; i < WI; ++i) {
                const int row = wr * (WI * 16) + i * 16 + l15;
                afh[i] = *(const f16x8*)&Ah[row * LDK + c * 32 + lq * 8];
            }
#pragma unroll
            for (int j = 0; j < 4; ++j) {
                const int bn = wc * 64 + j * 16 + l15;
                const f16x8 bfh = *(const f16x8*)&Bh[bn * LDK + c * 32 + lq * 8];
#pragma unroll
                for (int i = 0; i < WI; ++i)
                    acc[i][j] = __builtin_amdgcn_mfma_f32_16x16x32_f16(afh[i], bfh, acc[i][j], 0, 0, 0);
            }
        }
    }

#pragma unroll
    for (int j = 0; j < 4; ++j) {
        const int ng = n0 + wc * 64 + j * 16 + l15;
        const bool first = ng < Nsplit;
        const float bvf = first ? bias0[ng] : bias1[ng - Nsplit];
        const int nc = first ? ng : ng - Nsplit;
        const int ldc = first ? ld0 : ld1;
#pragma unroll
        for (int i = 0; i < WI; ++i) {
            const int mg = m0 + wr * (WI * 16) + i * 16 + lq * 4;
#pragma unroll
            for (int r = 0; r < 4; ++r) {
                const float v = (acc[i][j][r] + bvf) * outscale;
                if (OUT32)
                    ((float*)(first ? C0v : C1v))[(size_t)(mg + r) * ldc + nc] = v;
                else
                    ((f16*)(first ? C0v : C1v))[(size_t)(mg + r) * ldc + nc] = (f16)v;
            }
        }
    }
}

#define SHUF8(x, y) __builtin_shufflevector(x, y, 0, 1, 2, 3, 4, 5, 6, 7)

// ---------------------------------------------------------------------------
// fp16-MFMA flash attention v6.1 (unchanged from round 13 — passed):
// 4 waves x 32 q-rows, swapped QK^T (in-register P via cvt_pkrtz, zero P LDS),
// permuted V tr16 subtiles, per-q ballot-deferred softmax, double-buffered
// K/V via global_load_lds + counted vmcnt + raw barriers, f16 AO out.
// ---------------------------------------------------------------------------
__global__ __launch_bounds__(256, 2) void flash_attn_mfma(
    const f16* __restrict__ Q, const f16* __restrict__ Kp,
    const f16* __restrict__ Vp, f16* __restrict__ AOh)
{
    __shared__ f16 KsA[2][64 * 128];   // 32 KB
    __shared__ f16 VtA[2][64 * 128];   // 32 KB (tr16 subtiled, permuted rows)

    const int tid = threadIdx.x;
    const int w = tid >> 6, l = tid & 63;
    const int l15 = l & 15, lq = l >> 4;
    const int b = blockIdx.z, h = blockIdx.y, g = h >> 2;
    const int q0 = blockIdx.x << 7;    // 128 q-rows per block

    const f16* Qb = Q + (size_t)(b * SEQ + q0) * D_MODEL + h * HD;
    const f16* Kb = Kp + (size_t)b * SEQ * GHD + g * HD;
    const f16* Vb = Vp + (size_t)b * SEQ * GHD + g * HD;

    f16x8 aq[2][4];
#pragma unroll
    for (int rg = 0; rg < 2; ++rg) {
        const f16* qrow = Qb + (size_t)(w * 32 + rg * 16 + l15) * D_MODEL;
#pragma unroll
        for (int c = 0; c < 4; ++c)
            aq[rg][c] = *(const f16x8*)(qrow + c * 32 + lq * 8);
    }

    lf16* Ks3 = (lf16*)&KsA[0][0];
    lf16* Vt3 = (lf16*)&VtA[0][0];
    const f16* ksrc[4]; lf16* kdst[4];
    const f16* vsrc[4]; lf16* vdst[4];
#pragma unroll
    for (int i = 0; i < 4; ++i) {
        const int s = tid + (i << 8);
        {
            const int row = s >> 4, ul = s & 15;
            ksrc[i] = Kb + (size_t)row * GHD + ((ul ^ (row & 7)) << 3);
            kdst[i] = Ks3 + s * 8;
        }
        {
            const int dbit = s & 1, kvlo = (s >> 1) & 3, vlq = (s >> 3) & 3;
            const int jh = (s >> 5) & 1, kc = (s >> 6) & 1, dsub = s >> 7;
            const int kv = (kc << 5) | (jh << 4) | (vlq << 2) | kvlo;
            vsrc[i] = Vb + (size_t)kv * GHD + ((dsub << 4) | (dbit << 3));
            vdst[i] = Vt3 + s * 8;
        }
    }
    const unsigned vta0 = (unsigned)(size_t)(Vt3 + l * 4);
    const unsigned vta1 = vta0 + 16384;

    f32x4 acc_o[2][8];
#pragma unroll
    for (int rg = 0; rg < 2; ++rg)
#pragma unroll
        for (int i = 0; i < 8; ++i) acc_o[rg][i] = (f32x4){0.f, 0.f, 0.f, 0.f};
    float m_q[2] = {-1e30f, -1e30f};
    float l_q[2] = {0.f, 0.f};

    auto issue_tile = [&](int buf, int tile) {
        const size_t koff = (size_t)tile * 64 * GHD;
        const int KO = buf << 13;
#pragma unroll
        for (int i = 0; i < 4; ++i)
            __builtin_amdgcn_global_load_lds((gvoid*)(ksrc[i] + koff),
                                             (lvoid*)(kdst[i] + KO), 16, 0, 0);
#pragma unroll
        for (int i = 0; i < 4; ++i)
            __builtin_amdgcn_global_load_lds((gvoid*)(vsrc[i] + koff),
                                             (lvoid*)(vdst[i] + KO), 16, 0, 0);
    };

    auto compute_tile = [&](const f16* KsB, unsigned vtaB) {
        f32x4 sa[2][4];
        __builtin_amdgcn_s_setprio(1);
#pragma unroll
        for (int cb = 0; cb < 4; ++cb) {
            sa[0][cb] = (f32x4){0.f, 0.f, 0.f, 0.f};
            sa[1][cb] = (f32x4){0.f, 0.f, 0.f, 0.f};
#pragma unroll
            for (int c = 0; c < 4; ++c) {
                const int rk = cb * 16 + l15;
                const f16x8 bk = *(const f16x8*)&KsB[rk * 128 + (((c * 4 + lq) ^ (rk & 7)) << 3)];
                sa[0][cb] = __builtin_amdgcn_mfma_f32_16x16x32_f16(bk, aq[0][c], sa[0][cb], 0, 0, 0);
                sa[1][cb] = __builtin_amdgcn_mfma_f32_16x16x32_f16(bk, aq[1][c], sa[1][cb], 0, 0, 0);
            }
        }
        __builtin_amdgcn_s_setprio(0);

#pragma unroll
        for (int rg = 0; rg < 2; ++rg) {
            float gm = sa[rg][0][0];
#pragma unroll
            for (int cb = 0; cb < 4; ++cb)
#pragma unroll
                for (int reg = 0; reg < 4; ++reg)
                    gm = fmaxf(gm, sa[rg][cb][reg]);
            gm = fmaxf(gm, __shfl_xor(gm, 16));
            gm = fmaxf(gm, __shfl_xor(gm, 32));
            if (__ballot(gm > m_q[rg] + 11.5f)) {
                const float mnew = fmaxf(m_q[rg], gm);
                const float alpha = __builtin_amdgcn_exp2f(m_q[rg] - mnew);
                m_q[rg] = mnew;
                l_q[rg] *= alpha;
                f32x4 av;
#pragma unroll
                for (int reg = 0; reg < 4; ++reg)
                    av[reg] = __shfl(alpha, lq * 4 + reg);
#pragma unroll
                for (int db = 0; db < 8; ++db) acc_o[rg][db] *= av;
            }
        }

        f16x4 va0 = tr16<0>(vtaB),    vb0 = tr16<512>(vtaB);
        f16x4 va1 = tr16<1024>(vtaB), vb1 = tr16<1536>(vtaB);
        f16x4 ca0 = tr16<2048>(vtaB), cb0 = tr16<2560>(vtaB);
        f16x4 ca1 = tr16<3072>(vtaB), cb1 = tr16<3584>(vtaB);

        f16x8 pa[2][2];
#pragma unroll
        for (int rg = 0; rg < 2; ++rg) {
            float ps = 0.f;
#pragma unroll
            for (int cb = 0; cb < 4; ++cb)
#pragma unroll
                for (int reg = 0; reg < 4; ++reg) {
                    const float p = __builtin_amdgcn_exp2f(sa[rg][cb][reg] - m_q[rg]);
                    sa[rg][cb][reg] = p;
                    ps += p;
                }
            l_q[rg] += ps;
#pragma unroll
            for (int kc = 0; kc < 2; ++kc) {
                union { h16x2 h2[4]; f16x8 h8; } u;
                u.h2[0] = __builtin_amdgcn_cvt_pkrtz(sa[rg][2 * kc][0], sa[rg][2 * kc][1]);
                u.h2[1] = __builtin_amdgcn_cvt_pkrtz(sa[rg][2 * kc][2], sa[rg][2 * kc][3]);
                u.h2[2] = __builtin_amdgcn_cvt_pkrtz(sa[rg][2 * kc + 1][0], sa[rg][2 * kc + 1][1]);
                u.h2[3] = __builtin_amdgcn_cvt_pkrtz(sa[rg][2 * kc + 1][2], sa[rg][2 * kc + 1][3]);
                pa[rg][kc] = u.h8;
            }
        }

        WAIT_LGKM(4);
        f16x8 v0 = SHUF8(va0, vb0), v1 = SHUF8(va1, vb1);
#pragma unroll
        for (int db = 0; db < 8; ++db) {
            f16x4 ma0, mb0, ma1, mb1;
            if (db < 6) {
                switch (db) {
                case 0: ma0=tr16<4096>(vtaB);  mb0=tr16<4608>(vtaB);  ma1=tr16<5120>(vtaB);  mb1=tr16<5632>(vtaB);  break;
                case 1: ma0=tr16<6144>(vtaB);  mb0=tr16<6656>(vtaB);  ma1=tr16<7168>(vtaB);  mb1=tr16<7680>(vtaB);  break;
                case 2: ma0=tr16<8192>(vtaB);  mb0=tr16<8704>(vtaB);  ma1=tr16<9216>(vtaB);  mb1=tr16<9728>(vtaB);  break;
                case 3: ma0=tr16<10240>(vtaB); mb0=tr16<10752>(vtaB); ma1=tr16<11264>(vtaB); mb1=tr16<11776>(vtaB); break;
                case 4: ma0=tr16<12288>(vtaB); mb0=tr16<12800>(vtaB); ma1=tr16<13312>(vtaB); mb1=tr16<13824>(vtaB); break;
                default:ma0=tr16<14336>(vtaB); mb0=tr16<14848>(vtaB); ma1=tr16<15360>(vtaB); mb1=tr16<15872>(vtaB); break;
                }
                WAIT_LGKM(4);
            } else if (db == 6) {
                WAIT_LGKM(0);
            }
            f16x8 n0, n1;
            if (db < 7) { n0 = SHUF8(ca0, cb0); n1 = SHUF8(ca1, cb1); }
            __builtin_amdgcn_s_setprio(1);
            acc_o[0][db] = __builtin_amdgcn_mfma_f32_16x16x32_f16(pa[0][0], v0, acc_o[0][db], 0, 0, 0);
            acc_o[1][db] = __builtin_amdgcn_mfma_f32_16x16x32_f16(pa[1][0], v0, acc_o[1][db], 0, 0, 0);
            acc_o[0][db] = __builtin_amdgcn_mfma_f32_16x16x32_f16(pa[0][1], v1, acc_o[0][db], 0, 0, 0);
            acc_o[1][db] = __builtin_amdgcn_mfma_f32_16x16x32_f16(pa[1][1], v1, acc_o[1][db], 0, 0, 0);
            __builtin_amdgcn_s_setprio(0);
            if (db < 7) {
                v0 = n0; v1 = n1;
                ca0 = ma0; cb0 = mb0; ca1 = ma1; cb1 = mb1;
            }
        }
    };

    issue_tile(0, 0);
#pragma unroll 1
    for (int t2 = 0; t2 < 16; ++t2) {
        const int kt0 = t2 << 1;
        issue_tile(1, kt0 + 1);
        WAIT_VM8();
        BAR();
        compute_tile(&KsA[0][0], vta0);
        BAR();
        if (t2 < 15) {
            issue_tile(0, kt0 + 2);
            WAIT_VM8();
        } else {
            WAIT_VM0();
        }
        BAR();
        compute_tile(&KsA[1][0], vta1);
        BAR();
    }

    const size_t obase = (size_t)(b * SEQ + q0 + w * 32) * D_MODEL + h * HD;
#pragma unroll
    for (int rg = 0; rg < 2; ++rg) {
        float lr = l_q[rg];
        lr += __shfl_xor(lr, 16);
        lr += __shfl_xor(lr, 32);
        float inv_l[4];
#pragma unroll
        for (int reg = 0; reg < 4; ++reg)
            inv_l[reg] = 1.f / __shfl(lr, lq * 4 + reg);
#pragma unroll
        for (int db = 0; db < 8; ++db) {
#pragma unroll
            for (int reg = 0; reg < 4; ++reg) {
                const size_t off = obase + (size_t)(rg * 16 + lq * 4 + reg) * D_MODEL + db * 16 + l15;
                AOh[off] = (f16)(acc_o[rg][db][reg] * inv_l[reg]);
            }
        }
    }
}

extern "C" void kernel_launch(void* const* d_in, const int* in_sizes, int n_in,
                              void* d_out, int out_size, void* d_ws, size_t ws_size,
                              hipStream_t stream)
{
    const float* x  = (const float*)d_in[0];
    const float* Wq = (const float*)d_in[1];
    const float* bq = (const float*)d_in[2];
    const float* Wk = (const float*)d_in[3];
    const float* bk = (const float*)d_in[4];
    const float* Wv = (const float*)d_in[5];
    const float* bv = (const float*)d_in[6];
    const float* Wo = (const float*)d_in[7];
    const float* bo = (const float*)d_in[8];
    float* out = (float*)d_out;

    // workspace (f16 units), total 41,943,040 f16 = 83.9 MB (round-13 layout).
    // AOh aliases xh (x dead after Q/KV GEMMs); Wo^T reuses Wq^T slot.
    // Prefetch over-reads (<=4.2 KB past any array) stay inside d_ws.
    f16* base  = (f16*)d_ws;
    f16* xh    = base;                 // 8388608
    // [8388608, 16777216): slack
    f16* WkvT  = base + 16777216;      // 2097152 (K rows 0..511, V rows 512..1023)
    f16* WqoT  = base + 20971520;      // 4194304 (Wq, later Wo)
    f16* Qp    = base + 29360128;      // 8388608
    f16* Kp    = base + 37748736;      // 2097152
    f16* Vp    = base + 39845888;      // 2097152 -> end 41943040
    f16* AOh   = xh;

    const dim3 blk(256);
    // 1/sqrt(128) * log2(e): scores arrive in log2 units for exp2-direct softmax
    const float qscale = 0.08838834764831845f * 1.4426950408889634f;

    cast_f16<<<dim3(M_TOT * D_MODEL / 8 / 256), blk, 0, stream>>>(x, xh);
    transpose_cast<<<dim3(64, 64), blk, 0, stream>>>(Wq, WqoT, 2048, 2048, 0);
    transpose_cast<<<dim3(16, 64), blk, 0, stream>>>(Wk, WkvT, 2048, 512, 0);
    transpose_cast<<<dim3(16, 64), blk, 0, stream>>>(Wv, WkvT, 2048, 512, 512);

    // Q projection: 1-term f16 GEMM, BK=128, qscale folded
    gemm_bk<128, 128, false><<<dim3(16, 32), blk, 0, stream>>>(
        xh, WqoT, bq, bq, Qp, Qp, 2048, 2048, 2048, 2048, qscale);
    // K|V projection: 1-term f16 GEMM, BK=128
    gemm_bk<64, 128, false><<<dim3(16, 32), blk, 0, stream>>>(
        xh, WkvT, bk, bv, Kp, Vp, 512, 512, 512, 2048, 1.0f);

    // Wo^T into the (now dead) Wq^T slot, before attention overwrites xh
    transpose_cast<<<dim3(64, 64), blk, 0, stream>>>(Wo, WqoT, 2048, 2048, 0);

    flash_attn_mfma<<<dim3(SEQ / 128, NQH, B_SZ), blk, 0, stream>>>(Qp, Kp, Vp, AOh);

    // O projection: 1-term f16 GEMM, BK=128, fp32 out
    gemm_bk<128, 128, true><<<dim3(16, 32), blk, 0, stream>>>(
        AOh, WqoT, bo, bo, out, out, 2048, 2048, 2048, 2048, 1.0f);
}

// Round 16
// 220.700 us; speedup vs baseline: 1.0804x; 1.0328x over previous
//
#include <hip/hip_runtime.h>

#define D_MODEL 2048
#define GHD 512        // NUM_KV_GROUPS * HEAD_DIM
#define HD 128
#define NQH 16
#define B_SZ 2
#define SEQ 2048
#define M_TOT (B_SZ * SEQ)   // 4096

typedef _Float16 f16;
typedef __fp16 h16x2 __attribute__((ext_vector_type(2)));   // cvt_pkrtz native type
typedef _Float16 f16x4 __attribute__((ext_vector_type(4)));
typedef _Float16 f16x8 __attribute__((ext_vector_type(8)));
typedef float f32x4 __attribute__((ext_vector_type(4)));

typedef const __attribute__((address_space(1))) void gvoid;
typedef __attribute__((address_space(3))) void lvoid;
typedef __attribute__((address_space(3))) f16 lf16;

// raw barrier (no vmcnt(0) drain) with compiler fences
#define BAR() do { asm volatile("" ::: "memory"); \
                   __builtin_amdgcn_s_barrier();  \
                   asm volatile("" ::: "memory"); } while (0)
#define WAIT_VM8() asm volatile("s_waitcnt vmcnt(8)" ::: "memory")
#define WAIT_VM0() asm volatile("s_waitcnt vmcnt(0)" ::: "memory")
#define WAIT_LGKM(N) do { asm volatile("s_waitcnt lgkmcnt(" #N ")" ::: "memory"); \
                          __builtin_amdgcn_sched_barrier(0); } while (0)

// hardware transpose read: with per-lane addr = base + l*8B, lane l elem j
// reads f16 at base_f16[OFF/2 + (l>>4)*64 + j*16 + (l&15)]
template<int OFF>
__device__ __forceinline__ f16x4 tr16(unsigned a) {
    f16x4 d;
    asm volatile("ds_read_b64_tr_b16 %0, %1 offset:%2"
                 : "=v"(d) : "v"(a), "i"(OFF));
    return d;
}

// ---------------------------------------------------------------------------
// Merged prepass: one grid-routed dispatch replacing cast_f16 + 4 transposes.
// Segments (linear block id):
//   [0, 4096)      : x fp32 -> f16 (xh)
//   [4096, 8192)   : Wq^T  -> WqT  (32x32 tiles, 64x64 grid)
//   [8192, 12288)  : Wo^T  -> WoT
//   [12288, 13312) : Wk^T  -> WkvT rows 0..511   (16x64 grid)
//   [13312, 14336) : Wv^T  -> WkvT rows 512..1023
// ---------------------------------------------------------------------------
__global__ __launch_bounds__(256) void prep(
    const float* __restrict__ X,
    const float* __restrict__ Wq, const float* __restrict__ Wk,
    const float* __restrict__ Wv, const float* __restrict__ Wo,
    f16* __restrict__ Xh, f16* __restrict__ WqT,
    f16* __restrict__ WkvT, f16* __restrict__ WoT)
{
    __shared__ float Ls[32][33];
    const int bid = blockIdx.x;
    const int t = threadIdx.x;

    if (bid < 4096) {                       // ---- cast x
        const size_t i = ((size_t)bid * 256 + t) * 8;
        const float4 v0 = *(const float4*)(X + i);
        const float4 v1 = *(const float4*)(X + i + 4);
        f16x8 h;
        h[0] = (f16)v0.x; h[1] = (f16)v0.y; h[2] = (f16)v0.z; h[3] = (f16)v0.w;
        h[4] = (f16)v1.x; h[5] = (f16)v1.y; h[6] = (f16)v1.z; h[7] = (f16)v1.w;
        *(f16x8*)(Xh + i) = h;
        return;
    }

    // ---- transpose segments
    const float* W;
    f16* Th;
    int tb, n0, k0, N, row_off;
    if (bid < 8192)       { W = Wq; Th = WqT;  tb = bid - 4096;  N = 2048; row_off = 0;
                            n0 = (tb & 63) << 5; k0 = (tb >> 6) << 5; }
    else if (bid < 12288) { W = Wo; Th = WoT;  tb = bid - 8192;  N = 2048; row_off = 0;
                            n0 = (tb & 63) << 5; k0 = (tb >> 6) << 5; }
    else if (bid < 13312) { W = Wk; Th = WkvT; tb = bid - 12288; N = 512;  row_off = 0;
                            n0 = (tb & 15) << 5; k0 = (tb >> 4) << 5; }
    else                  { W = Wv; Th = WkvT; tb = bid - 13312; N = 512;  row_off = 512;
                            n0 = (tb & 15) << 5; k0 = (tb >> 4) << 5; }

    {
        const int kr = t >> 3, nq = (t & 7) << 2;
        const float4 v = *(const float4*)&W[(size_t)(k0 + kr) * N + n0 + nq];
        Ls[kr][nq + 0] = v.x; Ls[kr][nq + 1] = v.y;
        Ls[kr][nq + 2] = v.z; Ls[kr][nq + 3] = v.w;
    }
    __syncthreads();
    const int nr = t >> 3, kq = (t & 7) << 2;
    f16x4 hv;
#pragma unroll
    for (int e = 0; e < 4; ++e) hv[e] = (f16)Ls[kq + e][nr];
    *(f16x4*)&Th[(size_t)(row_off + n0 + nr) * 2048 + k0 + kq] = hv;
}

// ---------------------------------------------------------------------------
// 1-term f16 MFMA GEMM, templated BK. BM=128, 256 threads (4 waves).
// LDK=BK+8 pad (bank-uniform LDS ops). XCD-aware block swizzle (T1).
// Last-iter prefetch over-reads stay in d_ws.
// ---------------------------------------------------------------------------
template<int BN, int BK, bool OUT32>
__global__ __launch_bounds__(256) void gemm_bk(
    const f16* __restrict__ Agh,
    const f16* __restrict__ BTh,
    const float* __restrict__ bias0, const float* __restrict__ bias1,
    void* __restrict__ C0v, void* __restrict__ C1v,
    int Nsplit, int ld0, int ld1, int K, float outscale)
{
    constexpr int WN = BN / 64;           // waves along n
    constexpr int WM = 4 / WN;            // waves along m
    constexpr int WI = 128 / (WM * 16);   // m-frags per wave
    constexpr int LDK = BK + 8;           // padded row (f16)
    constexpr int CH  = BK / 8;           // 16B chunks per row
    constexpr int RPP = 256 / CH;         // rows staged per pass
    constexpr int AP  = 128 / RPP;        // A staging passes
    constexpr int BP  = BN / RPP;         // B staging passes
    constexpr int NC  = BK / 32;          // MFMA k-steps per tile

    __shared__ f16 Ah[128 * LDK];
    __shared__ f16 Bh[BN * LDK];

    const int tid = threadIdx.x;
    const int l = tid & 63, w = tid >> 6;
    const int l15 = l & 15, lq = l >> 4;
    const int wr = w / WN, wc = w % WN;

    // XCD swizzle: contiguous chunk of tiles per XCD (nwg = 512, div by 8)
    const int nwgx = gridDim.x;
    const int orig = blockIdx.y * nwgx + blockIdx.x;
    const int cpx = (nwgx * gridDim.y) >> 3;
    const int sw = (orig & 7) * cpx + (orig >> 3);
    const int m0 = (sw / nwgx) << 7;
    const int n0 = (sw % nwgx) * BN;

    f32x4 acc[WI][4];
#pragma unroll
    for (int i = 0; i < WI; ++i)
#pragma unroll
        for (int j = 0; j < 4; ++j) acc[i][j] = (f32x4){0.f, 0.f, 0.f, 0.f};

    const int srow = tid / CH;
    const int skc  = (tid % CH) * 8;
    const f16* Ap = Agh + (size_t)(m0 + srow) * K + skc;
    const f16* Bp = BTh + (size_t)(n0 + srow) * K + skc;

    f16x8 av[AP], bv[BP];
#pragma unroll
    for (int p = 0; p < AP; ++p)
        av[p] = *(const f16x8*)(Ap + (size_t)(p * RPP) * K);
#pragma unroll
    for (int p = 0; p < BP; ++p)
        bv[p] = *(const f16x8*)(Bp + (size_t)(p * RPP) * K);

    for (int k0 = 0; k0 < K; k0 += BK) {
        __syncthreads();   // previous iteration's fragment reads done
#pragma unroll
        for (int p = 0; p < AP; ++p)
            *(f16x8*)&Ah[(srow + p * RPP) * LDK + skc] = av[p];
#pragma unroll
        for (int p = 0; p < BP; ++p)
            *(f16x8*)&Bh[(srow + p * RPP) * LDK + skc] = bv[p];
        __syncthreads();

        // prefetch next k0 (flies under MFMA; last-iter over-read stays in ws)
        const int kn = k0 + BK;
#pragma unroll
        for (int p = 0; p < AP; ++p)
            av[p] = *(const f16x8*)(Ap + (size_t)(p * RPP) * K + kn);
#pragma unroll
        for (int p = 0; p < BP; ++p)
            bv[p] = *(const f16x8*)(Bp + (size_t)(p * RPP) * K + kn);

#pragma unroll
        for (int c = 0; c < NC; ++c) {
            f16x8 afh[WI];
#pragma unroll
            for (int i = 0; i < WI; ++i) {
                const int row = wr * (WI * 16) + i * 16 + l15;
                afh[i] = *(const f16x8*)&Ah[row * LDK + c * 32 + lq * 8];
            }
#pragma unroll
            for (int j = 0; j < 4; ++j) {
                const int bn = wc * 64 + j * 16 + l15;
                const f16x8 bfh = *(const f16x8*)&Bh[bn * LDK + c * 32 + lq * 8];
#pragma unroll
                for (int i = 0; i < WI; ++i)
                    acc[i][j] = __builtin_amdgcn_mfma_f32_16x16x32_f16(afh[i], bfh, acc[i][j], 0, 0, 0);
            }
        }
    }

#pragma unroll
    for (int j = 0; j < 4; ++j) {
        const int ng = n0 + wc * 64 + j * 16 + l15;
        const bool first = ng < Nsplit;
        const float bvf = first ? bias0[ng] : bias1[ng - Nsplit];
        const int nc = first ? ng : ng - Nsplit;
        const int ldc = first ? ld0 : ld1;
#pragma unroll
        for (int i = 0; i < WI; ++i) {
            const int mg = m0 + wr * (WI * 16) + i * 16 + lq * 4;
#pragma unroll
            for (int r = 0; r < 4; ++r) {
                const float v = (acc[i][j][r] + bvf) * outscale;
                if (OUT32)
                    ((float*)(first ? C0v : C1v))[(size_t)(mg + r) * ldc + nc] = v;
                else
                    ((f16*)(first ? C0v : C1v))[(size_t)(mg + r) * ldc + nc] = (f16)v;
            }
        }
    }
}

#define SHUF8(x, y) __builtin_shufflevector(x, y, 0, 1, 2, 3, 4, 5, 6, 7)

// ---------------------------------------------------------------------------
// fp16-MFMA flash attention v6.1 (unchanged — passed rounds 13-15):
// 4 waves x 32 q-rows, swapped QK^T (in-register P via cvt_pkrtz, zero P LDS),
// permuted V tr16 subtiles, per-q ballot-deferred softmax, double-buffered
// K/V via global_load_lds + counted vmcnt + raw barriers, f16 AO out.
// ---------------------------------------------------------------------------
__global__ __launch_bounds__(256, 2) void flash_attn_mfma(
    const f16* __restrict__ Q, const f16* __restrict__ Kp,
    const f16* __restrict__ Vp, f16* __restrict__ AOh)
{
    __shared__ f16 KsA[2][64 * 128];   // 32 KB
    __shared__ f16 VtA[2][64 * 128];   // 32 KB (tr16 subtiled, permuted rows)

    const int tid = threadIdx.x;
    const int w = tid >> 6, l = tid & 63;
    const int l15 = l & 15, lq = l >> 4;
    const int b = blockIdx.z, h = blockIdx.y, g = h >> 2;
    const int q0 = blockIdx.x << 7;    // 128 q-rows per block

    const f16* Qb = Q + (size_t)(b * SEQ + q0) * D_MODEL + h * HD;
    const f16* Kb = Kp + (size_t)b * SEQ * GHD + g * HD;
    const f16* Vb = Vp + (size_t)b * SEQ * GHD + g * HD;

    f16x8 aq[2][4];
#pragma unroll
    for (int rg = 0; rg < 2; ++rg) {
        const f16* qrow = Qb + (size_t)(w * 32 + rg * 16 + l15) * D_MODEL;
#pragma unroll
        for (int c = 0; c < 4; ++c)
            aq[rg][c] = *(const f16x8*)(qrow + c * 32 + lq * 8);
    }

    lf16* Ks3 = (lf16*)&KsA[0][0];
    lf16* Vt3 = (lf16*)&VtA[0][0];
    const f16* ksrc[4]; lf16* kdst[4];
    const f16* vsrc[4]; lf16* vdst[4];
#pragma unroll
    for (int i = 0; i < 4; ++i) {
        const int s = tid + (i << 8);
        {
            const int row = s >> 4, ul = s & 15;
            ksrc[i] = Kb + (size_t)row * GHD + ((ul ^ (row & 7)) << 3);
            kdst[i] = Ks3 + s * 8;
        }
        {
            const int dbit = s & 1, kvlo = (s >> 1) & 3, vlq = (s >> 3) & 3;
            const int jh = (s >> 5) & 1, kc = (s >> 6) & 1, dsub = s >> 7;
            const int kv = (kc << 5) | (jh << 4) | (vlq << 2) | kvlo;
            vsrc[i] = Vb + (size_t)kv * GHD + ((dsub << 4) | (dbit << 3));
            vdst[i] = Vt3 + s * 8;
        }
    }
    const unsigned vta0 = (unsigned)(size_t)(Vt3 + l * 4);
    const unsigned vta1 = vta0 + 16384;

    f32x4 acc_o[2][8];
#pragma unroll
    for (int rg = 0; rg < 2; ++rg)
#pragma unroll
        for (int i = 0; i < 8; ++i) acc_o[rg][i] = (f32x4){0.f, 0.f, 0.f, 0.f};
    float m_q[2] = {-1e30f, -1e30f};
    float l_q[2] = {0.f, 0.f};

    auto issue_tile = [&](int buf, int tile) {
        const size_t koff = (size_t)tile * 64 * GHD;
        const int KO = buf << 13;
#pragma unroll
        for (int i = 0; i < 4; ++i)
            __builtin_amdgcn_global_load_lds((gvoid*)(ksrc[i] + koff),
                                             (lvoid*)(kdst[i] + KO), 16, 0, 0);
#pragma unroll
        for (int i = 0; i < 4; ++i)
            __builtin_amdgcn_global_load_lds((gvoid*)(vsrc[i] + koff),
                                             (lvoid*)(vdst[i] + KO), 16, 0, 0);
    };

    auto compute_tile = [&](const f16* KsB, unsigned vtaB) {
        f32x4 sa[2][4];
        __builtin_amdgcn_s_setprio(1);
#pragma unroll
        for (int cb = 0; cb < 4; ++cb) {
            sa[0][cb] = (f32x4){0.f, 0.f, 0.f, 0.f};
            sa[1][cb] = (f32x4){0.f, 0.f, 0.f, 0.f};
#pragma unroll
            for (int c = 0; c < 4; ++c) {
                const int rk = cb * 16 + l15;
                const f16x8 bk = *(const f16x8*)&KsB[rk * 128 + (((c * 4 + lq) ^ (rk & 7)) << 3)];
                sa[0][cb] = __builtin_amdgcn_mfma_f32_16x16x32_f16(bk, aq[0][c], sa[0][cb], 0, 0, 0);
                sa[1][cb] = __builtin_amdgcn_mfma_f32_16x16x32_f16(bk, aq[1][c], sa[1][cb], 0, 0, 0);
            }
        }
        __builtin_amdgcn_s_setprio(0);

#pragma unroll
        for (int rg = 0; rg < 2; ++rg) {
            float gm = sa[rg][0][0];
#pragma unroll
            for (int cb = 0; cb < 4; ++cb)
#pragma unroll
                for (int reg = 0; reg < 4; ++reg)
                    gm = fmaxf(gm, sa[rg][cb][reg]);
            gm = fmaxf(gm, __shfl_xor(gm, 16));
            gm = fmaxf(gm, __shfl_xor(gm, 32));
            if (__ballot(gm > m_q[rg] + 11.5f)) {
                const float mnew = fmaxf(m_q[rg], gm);
                const float alpha = __builtin_amdgcn_exp2f(m_q[rg] - mnew);
                m_q[rg] = mnew;
                l_q[rg] *= alpha;
                f32x4 av;
#pragma unroll
                for (int reg = 0; reg < 4; ++reg)
                    av[reg] = __shfl(alpha, lq * 4 + reg);
#pragma unroll
                for (int db = 0; db < 8; ++db) acc_o[rg][db] *= av;
            }
        }

        f16x4 va0 = tr16<0>(vtaB),    vb0 = tr16<512>(vtaB);
        f16x4 va1 = tr16<1024>(vtaB), vb1 = tr16<1536>(vtaB);
        f16x4 ca0 = tr16<2048>(vtaB), cb0 = tr16<2560>(vtaB);
        f16x4 ca1 = tr16<3072>(vtaB), cb1 = tr16<3584>(vtaB);

        f16x8 pa[2][2];
#pragma unroll
        for (int rg = 0; rg < 2; ++rg) {
            float ps = 0.f;
#pragma unroll
            for (int cb = 0; cb < 4; ++cb)
#pragma unroll
                for (int reg = 0; reg < 4; ++reg) {
                    const float p = __builtin_amdgcn_exp2f(sa[rg][cb][reg] - m_q[rg]);
                    sa[rg][cb][reg] = p;
                    ps += p;
                }
            l_q[rg] += ps;
#pragma unroll
            for (int kc = 0; kc < 2; ++kc) {
                union { h16x2 h2[4]; f16x8 h8; } u;
                u.h2[0] = __builtin_amdgcn_cvt_pkrtz(sa[rg][2 * kc][0], sa[rg][2 * kc][1]);
                u.h2[1] = __builtin_amdgcn_cvt_pkrtz(sa[rg][2 * kc][2], sa[rg][2 * kc][3]);
                u.h2[2] = __builtin_amdgcn_cvt_pkrtz(sa[rg][2 * kc + 1][0], sa[rg][2 * kc + 1][1]);
                u.h2[3] = __builtin_amdgcn_cvt_pkrtz(sa[rg][2 * kc + 1][2], sa[rg][2 * kc + 1][3]);
                pa[rg][kc] = u.h8;
            }
        }

        WAIT_LGKM(4);
        f16x8 v0 = SHUF8(va0, vb0), v1 = SHUF8(va1, vb1);
#pragma unroll
        for (int db = 0; db < 8; ++db) {
            f16x4 ma0, mb0, ma1, mb1;
            if (db < 6) {
                switch (db) {
                case 0: ma0=tr16<4096>(vtaB);  mb0=tr16<4608>(vtaB);  ma1=tr16<5120>(vtaB);  mb1=tr16<5632>(vtaB);  break;
                case 1: ma0=tr16<6144>(vtaB);  mb0=tr16<6656>(vtaB);  ma1=tr16<7168>(vtaB);  mb1=tr16<7680>(vtaB);  break;
                case 2: ma0=tr16<8192>(vtaB);  mb0=tr16<8704>(vtaB);  ma1=tr16<9216>(vtaB);  mb1=tr16<9728>(vtaB);  break;
                case 3: ma0=tr16<10240>(vtaB); mb0=tr16<10752>(vtaB); ma1=tr16<11264>(vtaB); mb1=tr16<11776>(vtaB); break;
                case 4: ma0=tr16<12288>(vtaB); mb0=tr16<12800>(vtaB); ma1=tr16<13312>(vtaB); mb1=tr16<13824>(vtaB); break;
                default:ma0=tr16<14336>(vtaB); mb0=tr16<14848>(vtaB); ma1=tr16<15360>(vtaB); mb1=tr16<15872>(vtaB); break;
                }
                WAIT_LGKM(4);
            } else if (db == 6) {
                WAIT_LGKM(0);
            }
            f16x8 n0, n1;
            if (db < 7) { n0 = SHUF8(ca0, cb0); n1 = SHUF8(ca1, cb1); }
            __builtin_amdgcn_s_setprio(1);
            acc_o[0][db] = __builtin_amdgcn_mfma_f32_16x16x32_f16(pa[0][0], v0, acc_o[0][db], 0, 0, 0);
            acc_o[1][db] = __builtin_amdgcn_mfma_f32_16x16x32_f16(pa[1][0], v0, acc_o[1][db], 0, 0, 0);
            acc_o[0][db] = __builtin_amdgcn_mfma_f32_16x16x32_f16(pa[0][1], v1, acc_o[0][db], 0, 0, 0);
            acc_o[1][db] = __builtin_amdgcn_mfma_f32_16x16x32_f16(pa[1][1], v1, acc_o[1][db], 0, 0, 0);
            __builtin_amdgcn_s_setprio(0);
            if (db < 7) {
                v0 = n0; v1 = n1;
                ca0 = ma0; cb0 = mb0; ca1 = ma1; cb1 = mb1;
            }
        }
    };

    issue_tile(0, 0);
#pragma unroll 1
    for (int t2 = 0; t2 < 16; ++t2) {
        const int kt0 = t2 << 1;
        issue_tile(1, kt0 + 1);
        WAIT_VM8();
        BAR();
        compute_tile(&KsA[0][0], vta0);
        BAR();
        if (t2 < 15) {
            issue_tile(0, kt0 + 2);
            WAIT_VM8();
        } else {
            WAIT_VM0();
        }
        BAR();
        compute_tile(&KsA[1][0], vta1);
        BAR();
    }

    const size_t obase = (size_t)(b * SEQ + q0 + w * 32) * D_MODEL + h * HD;
#pragma unroll
    for (int rg = 0; rg < 2; ++rg) {
        float lr = l_q[rg];
        lr += __shfl_xor(lr, 16);
        lr += __shfl_xor(lr, 32);
        float inv_l[4];
#pragma unroll
        for (int reg = 0; reg < 4; ++reg)
            inv_l[reg] = 1.f / __shfl(lr, lq * 4 + reg);
#pragma unroll
        for (int db = 0; db < 8; ++db) {
#pragma unroll
            for (int reg = 0; reg < 4; ++reg) {
                const size_t off = obase + (size_t)(rg * 16 + lq * 4 + reg) * D_MODEL + db * 16 + l15;
                AOh[off] = (f16)(acc_o[rg][db][reg] * inv_l[reg]);
            }
        }
    }
}

extern "C" void kernel_launch(void* const* d_in, const int* in_sizes, int n_in,
                              void* d_out, int out_size, void* d_ws, size_t ws_size,
                              hipStream_t stream)
{
    const float* x  = (const float*)d_in[0];
    const float* Wq = (const float*)d_in[1];
    const float* bq = (const float*)d_in[2];
    const float* Wk = (const float*)d_in[3];
    const float* bk = (const float*)d_in[4];
    const float* Wv = (const float*)d_in[5];
    const float* bv = (const float*)d_in[6];
    const float* Wo = (const float*)d_in[7];
    const float* bo = (const float*)d_in[8];
    float* out = (float*)d_out;

    // workspace (f16 units), total 41,943,040 f16 = 83.9 MB.
    // WoT gets its own slot (prep writes it before Q-GEMM reads WqT).
    // AOh aliases xh (x dead after Q/KV GEMMs).
    // Prefetch over-reads (<=4.2 KB past any array) stay inside d_ws.
    f16* base  = (f16*)d_ws;
    f16* xh    = base;                 // 8388608
    f16* WoT   = base + 8388608;       // 4194304
    // [12582912, 16777216): slack
    f16* WkvT  = base + 16777216;      // 2097152 (K rows 0..511, V rows 512..1023)
    f16* WqT   = base + 20971520;      // 4194304
    f16* Qp    = base + 29360128;      // 8388608
    f16* Kp    = base + 37748736;      // 2097152
    f16* Vp    = base + 39845888;      // 2097152 -> end 41943040
    f16* AOh   = xh;

    const dim3 blk(256);
    // 1/sqrt(128) * log2(e): scores arrive in log2 units for exp2-direct softmax
    const float qscale = 0.08838834764831845f * 1.4426950408889634f;

    // merged prepass: cast + all 4 weight transposes, one dispatch
    prep<<<dim3(14336), blk, 0, stream>>>(x, Wq, Wk, Wv, Wo, xh, WqT, WkvT, WoT);

    // Q projection: 1-term f16 GEMM, BK=128, qscale folded
    gemm_bk<128, 128, false><<<dim3(16, 32), blk, 0, stream>>>(
        xh, WqT, bq, bq, Qp, Qp, 2048, 2048, 2048, 2048, qscale);
    // K|V projection: 1-term f16 GEMM, BK=128
    gemm_bk<64, 128, false><<<dim3(16, 32), blk, 0, stream>>>(
        xh, WkvT, bk, bv, Kp, Vp, 512, 512, 512, 2048, 1.0f);

    flash_attn_mfma<<<dim3(SEQ / 128, NQH, B_SZ), blk, 0, stream>>>(Qp, Kp, Vp, AOh);

    // O projection: 1-term f16 GEMM, BK=128, fp32 out
    gemm_bk<128, 128, true><<<dim3(16, 32), blk, 0, stream>>>(
        AOh, WoT, bo, bo, out, out, 2048, 2048, 2048, 2048, 1.0f);
}